// Round 4
// baseline (335.782 us; speedup 1.0000x reference)
//
#include <hip/hip_runtime.h>
#include <hip/hip_cooperative_groups.h>

// GraphConvolution_relative: out = relu(einsum('sn,sd->nd', diag, w))
// diag[s,i] = sum_{e: rows[s,e]==i} vals[s,e] * |x[r,c] + x[c,r]|
//
// Round 4: single cooperative kernel fusing zero + edge-scatter + epilogue.
// Grid = 2048 blocks x 256 = 524288 threads = exactly one edge per thread,
// and exactly 32 waves/CU resident (cooperative-launch requirement).
// Gather phase is at the compulsory-miss wall (~860K distinct lines, reuse~1.2);
// this round removes the 2 kernel boundaries + memset dispatch.

namespace cg = cooperative_groups;

#define N_NODES 8192
#define S_SUP   2
#define E_EDGES 262144   // 2^18
#define D_OUT   128

__global__ __launch_bounds__(256, 8)
void gc_fused_kernel(const float* __restrict__ x,
                     const int*   __restrict__ rows,
                     const int*   __restrict__ cols,
                     const float* __restrict__ vals,
                     const float* __restrict__ w,
                     float*       __restrict__ out,
                     float*       __restrict__ diag) {
    cg::grid_group grid = cg::this_grid();
    int idx = blockIdx.x * blockDim.x + threadIdx.x;   // 0 .. 524287

    // ---- phase 0: zero the accumulator (first 16384 threads) ----
    if (idx < S_SUP * N_NODES) diag[idx] = 0.0f;
    grid.sync();

    // ---- phase 1: edge scatter (one edge per thread) ----
    {
        int s = idx >> 18;                 // idx / E_EDGES
        int r = rows[idx];
        int c = cols[idx];
        float v = vals[idx];
        float a = __builtin_nontemporal_load(&x[(r << 13) | c]);
        float b = __builtin_nontemporal_load(&x[(c << 13) | r]);
        atomicAdd(&diag[(s << 13) + r], fabsf(a + b) * v);
    }
    grid.sync();

    // ---- phase 2: epilogue out[n][d] = relu(d0*w0[d] + d1*w1[d]) ----
    if (idx < N_NODES * D_OUT / 4) {
        int d4 = idx & (D_OUT / 4 - 1);                // 0..31
        int n  = idx >> 5;
        float d0 = diag[n];
        float d1 = diag[N_NODES + n];
        const float4 w0 = ((const float4*)w)[d4];               // w[0][d..d+3]
        const float4 w1 = ((const float4*)w)[D_OUT / 4 + d4];   // w[1][d..d+3]
        float4 o;
        o.x = fmaxf(fmaf(d0, w0.x, d1 * w1.x), 0.0f);
        o.y = fmaxf(fmaf(d0, w0.y, d1 * w1.y), 0.0f);
        o.z = fmaxf(fmaf(d0, w0.z, d1 * w1.z), 0.0f);
        o.w = fmaxf(fmaf(d0, w0.w, d1 * w1.w), 0.0f);
        ((float4*)out)[idx] = o;
    }
}

extern "C" void kernel_launch(void* const* d_in, const int* in_sizes, int n_in,
                              void* d_out, int out_size, void* d_ws, size_t ws_size,
                              hipStream_t stream) {
    const float* x    = (const float*)d_in[0];
    const int*   rows = (const int*)  d_in[1];
    const int*   cols = (const int*)  d_in[2];
    const float* vals = (const float*)d_in[3];
    const float* w    = (const float*)d_in[4];
    float* out  = (float*)d_out;
    float* diag = (float*)d_ws;   // S_SUP * N_NODES floats = 64 KB

    void* args[] = { (void*)&x, (void*)&rows, (void*)&cols, (void*)&vals,
                     (void*)&w, (void*)&out, (void*)&diag };
    dim3 grid(S_SUP * E_EDGES / 256);   // 2048 blocks
    dim3 block(256);
    hipLaunchCooperativeKernel((void*)gc_fused_kernel, grid, block, args, 0, stream);
}

// Round 6
// 44.291 us; speedup vs baseline: 7.5813x; 7.5813x over previous
//
#include <hip/hip_runtime.h>

// GraphConvolution_relative: out = relu(einsum('sn,sd->nd', diag, w))
// diag[s,i] = sum_{e: rows[s,e]==i} vals[s,e] * |x[r,c] + x[c,r]|
//
// Round 6 (= round-5 with compile fix): 3-dispatch structure. Cache-hint flip:
//  - x gathers: PLAIN loads (let L2/L3 retain the ~103MB hot-line set; round-4
//    counters showed nt gathers refetched 68MB from HBM every replay)
//  - edge streams rows/cols/vals: nontemporal (zero reuse within a replay)
//  - out store: nontemporal (write-only) — via native ext_vector_type
//    (HIP's float4 class is rejected by __builtin_nontemporal_store)

#define N_NODES 8192
#define S_SUP   2
#define E_EDGES 262144   // 2^18
#define D_OUT   128

typedef float vfloat4 __attribute__((ext_vector_type(4)));

__global__ __launch_bounds__(256)
void gc_edge_kernel(const float* __restrict__ x,
                    const int*   __restrict__ rows,
                    const int*   __restrict__ cols,
                    const float* __restrict__ vals,
                    float*       __restrict__ diag) {
    int idx = blockIdx.x * blockDim.x + threadIdx.x;
    if (idx >= S_SUP * E_EDGES) return;
    int s = idx >> 18;                 // idx / E_EDGES
    int r = __builtin_nontemporal_load(&rows[idx]);
    int c = __builtin_nontemporal_load(&cols[idx]);
    float v = __builtin_nontemporal_load(&vals[idx]);
    float a = x[(r << 13) | c];        // plain: allow L2/L3 allocation
    float b = x[(c << 13) | r];
    float t = fabsf(a + b) * v;
    atomicAdd(&diag[(s << 13) + r], t);
}

__global__ __launch_bounds__(256)
void gc_out_kernel(const float* __restrict__ diag,
                   const float* __restrict__ w,
                   float*       __restrict__ out) {
    int idx = blockIdx.x * blockDim.x + threadIdx.x;   // over N*D/4
    int d4 = idx & (D_OUT / 4 - 1);                    // 0..31
    int n  = idx >> 5;
    if (n >= N_NODES) return;
    float d0 = diag[n];
    float d1 = diag[N_NODES + n];
    const float4 w0 = ((const float4*)w)[d4];               // w[0][d..d+3]
    const float4 w1 = ((const float4*)w)[D_OUT / 4 + d4];   // w[1][d..d+3]
    vfloat4 o;
    o.x = fmaxf(fmaf(d0, w0.x, d1 * w1.x), 0.0f);
    o.y = fmaxf(fmaf(d0, w0.y, d1 * w1.y), 0.0f);
    o.z = fmaxf(fmaf(d0, w0.z, d1 * w1.z), 0.0f);
    o.w = fmaxf(fmaf(d0, w0.w, d1 * w1.w), 0.0f);
    __builtin_nontemporal_store(o, &((vfloat4*)out)[idx]);
}

extern "C" void kernel_launch(void* const* d_in, const int* in_sizes, int n_in,
                              void* d_out, int out_size, void* d_ws, size_t ws_size,
                              hipStream_t stream) {
    const float* x    = (const float*)d_in[0];
    const int*   rows = (const int*)  d_in[1];
    const int*   cols = (const int*)  d_in[2];
    const float* vals = (const float*)d_in[3];
    const float* w    = (const float*)d_in[4];
    float* out  = (float*)d_out;
    float* diag = (float*)d_ws;   // S_SUP * N_NODES floats = 64 KB

    hipMemsetAsync(diag, 0, (size_t)S_SUP * N_NODES * sizeof(float), stream);

    {
        int total = S_SUP * E_EDGES;
        int block = 256;
        int grid  = (total + block - 1) / block;
        gc_edge_kernel<<<grid, block, 0, stream>>>(x, rows, cols, vals, diag);
    }
    {
        int total = N_NODES * D_OUT / 4;
        int block = 256;
        int grid  = (total + block - 1) / block;
        gc_out_kernel<<<grid, block, 0, stream>>>(diag, w, out);
    }
}